// Round 5
// baseline (120.655 us; speedup 1.0000x reference)
//
#include <hip/hip_runtime.h>
#include <stdint.h>

// Problem constants (fixed by setup_inputs): B=32, N=512, D=512
#define BATCH 32
#define NDIM 512
#define DDIM 512
#define XELEMS (BATCH * NDIM * DDIM)   // 8388608
#define WELEMS (DDIM * DDIM)           // 262144

typedef _Float16 f16x8 __attribute__((ext_vector_type(8)));
typedef _Float16 f16x4v __attribute__((ext_vector_type(4)));
typedef float f32x4 __attribute__((ext_vector_type(4)));

// --- async global -> LDS, 16 bytes per lane (global_load_lds_dwordx4) ---
__device__ __forceinline__ void gl_lds16(const _Float16* g, _Float16* l) {
    __builtin_amdgcn_global_load_lds(
        (const __attribute__((address_space(1))) unsigned int*)(g),
        (__attribute__((address_space(3))) unsigned int*)(l),
        16, 0, 0);
}

// ---------------- pass 0: X fp32->fp16 convert  +  W fp32->fp16 transpose ----------
// (unchanged from the 112.8 µs verified kernel)
__global__ __launch_bounds__(256) void prep(const float4* __restrict__ X4,
                                            f16x4v* __restrict__ Xh4,
                                            const float* __restrict__ W,
                                            _Float16* __restrict__ Wt) {
    __shared__ float tile[32][33];
    int bid = blockIdx.x;
    if (bid < XELEMS / 4 / 256) {
        int i = bid * 256 + threadIdx.x;
        float4 v = X4[i];
        f16x4v o;
        o.x = (_Float16)v.x;
        o.y = (_Float16)v.y;
        o.z = (_Float16)v.z;
        o.w = (_Float16)v.w;
        Xh4[i] = o;
    } else {
        int t = bid - XELEMS / 4 / 256;   // 0..255
        int bx = t & 15;                  // e-tile
        int by = t >> 4;                  // d-tile
        int tx = threadIdx.x & 31;
        int ty = threadIdx.x >> 5;        // 0..7
        for (int r = ty; r < 32; r += 8)
            tile[r][tx] = W[(by * 32 + r) * DDIM + bx * 32 + tx];
        __syncthreads();
        for (int r = ty; r < 32; r += 8)
            Wt[(size_t)(bx * 32 + r) * DDIM + by * 32 + tx] = (_Float16)tile[tx][r];
    }
}

// ---------------- fused: S_b = (X_b @ W) @ X_b^T + bias, diag = 0 -------------------
// [R2/R3/R4: PIPELINED rewrite of the R1 fused kernel (R3/R4 = resubmits after
//  GPUAcquisitionTimeout infra failures; kernel has never executed). R1 counters:
//  45.5 µs, MfmaUtil 12.8, VALUBusy 8.4, HBM 12%, occupancy 18.5 -> latency-bound:
//  6800 cyc/K-iter vs ~300 of compute, because
//  `stage -> __syncthreads (vmcnt(0) drain) -> compute` exposes the full staging
//  latency every iter at 1 block/CU (no inter-block overlap).
//  Fix = T3-minimum template: BK 64->32 so Bs double-buffers in the SAME 136 KB
//  (Ylds 64K + As 2x4K + Bs 2x32K). Per iter: stage(t+1, buf^1) -> compute(buf) ->
//  one __syncthreads (drain lands AFTER compute). Phase-2 tile 0 prefetched under
//  phase-1's last compute. K-order unchanged -> bit-identical accumulation.
//  BK=32 swizzle: chunk = 16 rows x 32 cols; physical 16B slot p at row r holds
//  logical k-chunk p ^ ((r>>1)&3) — read bank-starts collide only 2-way (l16 vs
//  l16+8), the wave64 b128 minimum (free, m136).]
//
// Grid: 256 blocks = rs*32 + batch  (blk%8 = batch%8 -> a batch's 8 row-slice blocks
// share one XCD -> X_b (512 KB, read twice) is L2-resident; Wt resident everywhere).
__global__ __launch_bounds__(512) void fused(const _Float16* __restrict__ Xh,
                                             const _Float16* __restrict__ Wt,
                                             float* __restrict__ Sout,
                                             const float* __restrict__ bias_ptr) {
    __shared__ __align__(16) _Float16 Ylds[64 * 512];     // 64 KB
    __shared__ __align__(16) _Float16 As2[2][64 * 32];    //  8 KB (2x4K)
    __shared__ __align__(16) _Float16 Bs2[2][512 * 32];   // 64 KB (2x32K)

    const int tid  = threadIdx.x;
    const int lane = tid & 63;
    const int wv   = tid >> 6;        // 0..7
    const int quad = lane >> 4;       // 0..3
    const int l16  = lane & 15;

    // staging decomposition (BK=32): one wave-issue = 16 rows x 32 cols (1 KB).
    const int lr2 = lane >> 2;                    // row within chunk (0..15)
    const int lc2 = lane & 3;                     // physical 16B slot (0..3)
    const int lk2 = (lc2 ^ ((lr2 >> 1) & 3)) * 8; // logical fp16 col to fetch (rule 21)

    // fragment read slot (read side of the same involution; frag rows ≡ l16 mod 16)
    const int paK = (quad ^ ((l16 >> 1) & 3)) * 8;

    const int blk   = blockIdx.x;     // 256 blocks
    const int batch = blk & 31;
    const int r0    = (blk >> 5) * 64;

    const _Float16* Xb = Xh + (size_t)batch * (NDIM * DDIM);

    f32x4 acc[4][4];
#pragma unroll
    for (int i = 0; i < 4; ++i)
#pragma unroll
        for (int j = 0; j < 4; ++j)
            acc[i][j] = (f32x4){0.f, 0.f, 0.f, 0.f};

    // ---- prologue: stage phase-1 tile 0 into buffer 0
    if (wv < 4)
        gl_lds16(Xb + (size_t)(r0 + wv * 16 + lr2) * DDIM + lk2, &As2[0][wv * 512]);
#pragma unroll
    for (int t = 0; t < 4; ++t) {
        const int chunk = wv * 4 + t;
        gl_lds16(Wt + (size_t)(chunk * 16 + lr2) * DDIM + lk2, &Bs2[0][chunk * 512]);
    }
    __syncthreads();

    // ================= phase 1: Y = X_b[r0:r0+64][:] @ Wt^T  (16 iters, BK=32) =====
    int buf = 0;
    for (int it = 0; it < 16; ++it) {
        if (it < 15) {                 // stage next K-tile
            const int k0 = (it + 1) * 32;
            if (wv < 4)
                gl_lds16(Xb + (size_t)(r0 + wv * 16 + lr2) * DDIM + k0 + lk2,
                         &As2[buf ^ 1][wv * 512]);
#pragma unroll
            for (int t = 0; t < 4; ++t) {
                const int chunk = wv * 4 + t;
                gl_lds16(Wt + (size_t)(chunk * 16 + lr2) * DDIM + k0 + lk2,
                         &Bs2[buf ^ 1][chunk * 512]);
            }
        } else {                       // prefetch phase-2 tile 0 (Bs only)
#pragma unroll
            for (int t = 0; t < 4; ++t) {
                const int chunk = wv * 4 + t;
                gl_lds16(Xb + (size_t)(chunk * 16 + lr2) * DDIM + lk2,
                         &Bs2[buf ^ 1][chunk * 512]);
            }
        }

        // compute current tile (one K-step of 32)
        {
            f16x8 a[4], b[4];
#pragma unroll
            for (int mt = 0; mt < 4; ++mt)
                a[mt] = *(const f16x8*)&As2[buf][(mt * 16 + l16) * 32 + paK];
#pragma unroll
            for (int nt = 0; nt < 4; ++nt)
                b[nt] = *(const f16x8*)&Bs2[buf][(wv * 64 + nt * 16 + l16) * 32 + paK];
#pragma unroll
            for (int mt = 0; mt < 4; ++mt)
#pragma unroll
                for (int nt = 0; nt < 4; ++nt)
                    acc[mt][nt] = __builtin_amdgcn_mfma_f32_16x16x32_f16(
                        a[mt], b[nt], acc[mt][nt], 0, 0, 0);
        }
        __syncthreads();   // drains this iter's stage AFTER compute; publishes buf^1
        buf ^= 1;
    }

    // ---- Y -> Ylds (fp16), e-chunk XOR-swizzled (unchanged, verified in R1).
    // C/D layout: col = l16, row = quad*4 + r  (m89-verified).
#pragma unroll
    for (int mt = 0; mt < 4; ++mt)
#pragma unroll
        for (int nt = 0; nt < 4; ++nt)
#pragma unroll
            for (int r = 0; r < 4; ++r) {
                int i = mt * 16 + quad * 4 + r;        // Y row (0..63)
                int e = wv * 64 + nt * 16 + l16;       // Y col (0..511)
                int c = e >> 3, j = e & 7;
                Ylds[i * 512 + (((c ^ (i & 7)) << 3) | j)] = (_Float16)acc[mt][nt][r];
            }
    __syncthreads();   // publishes Ylds; also drains the phase-2 tile-0 prefetch

    // ================= phase 2: S = Y @ X_b^T  (16 iters, BK=32) ===================
#pragma unroll
    for (int i = 0; i < 4; ++i)
#pragma unroll
        for (int j = 0; j < 4; ++j)
            acc[i][j] = (f32x4){0.f, 0.f, 0.f, 0.f};

    for (int it = 0; it < 16; ++it) {
        if (it < 15) {                 // stage next e-tile of X_b
            const int e0 = (it + 1) * 32;
#pragma unroll
            for (int t = 0; t < 4; ++t) {
                const int chunk = wv * 4 + t;
                gl_lds16(Xb + (size_t)(chunk * 16 + lr2) * DDIM + e0 + lk2,
                         &Bs2[buf ^ 1][chunk * 512]);
            }
        }

        {
            const int pay = (((it * 4 + quad) ^ (l16 & 7)) * 8);  // Ylds swizzled col
            f16x8 a[4], b[4];
#pragma unroll
            for (int mt = 0; mt < 4; ++mt)
                a[mt] = *(const f16x8*)&Ylds[(mt * 16 + l16) * 512 + pay];
#pragma unroll
            for (int nt = 0; nt < 4; ++nt)
                b[nt] = *(const f16x8*)&Bs2[buf][(wv * 64 + nt * 16 + l16) * 32 + paK];
#pragma unroll
            for (int mt = 0; mt < 4; ++mt)
#pragma unroll
                for (int nt = 0; nt < 4; ++nt)
                    acc[mt][nt] = __builtin_amdgcn_mfma_f32_16x16x32_f16(
                        a[mt], b[nt], acc[mt][nt], 0, 0, 0);
        }
        __syncthreads();
        buf ^= 1;
    }

    // ---- epilogue: bias, zero diagonal, fp32 store
    const float bias = bias_ptr[0];
#pragma unroll
    for (int mt = 0; mt < 4; ++mt)
#pragma unroll
        for (int nt = 0; nt < 4; ++nt)
#pragma unroll
            for (int r = 0; r < 4; ++r) {
                int gi = r0 + mt * 16 + quad * 4 + r;   // row within batch (0..511)
                int gj = wv * 64 + nt * 16 + l16;       // col within batch (0..511)
                float v = acc[mt][nt][r] + bias;
                if (gi == gj) v = 0.f;
                Sout[((size_t)batch * NDIM + gi) * NDIM + gj] = v;
            }
}

extern "C" void kernel_launch(void* const* d_in, const int* in_sizes, int n_in,
                              void* d_out, int out_size, void* d_ws, size_t ws_size,
                              hipStream_t stream) {
    const float* X  = (const float*)d_in[0];   // (32, 512, 512) fp32
    const float* W  = (const float*)d_in[1];   // (512, 512) fp32
    const float* bp = (const float*)d_in[2];   // scalar fp32
    float* out = (float*)d_out;                // (32, 512, 512) fp32

    // workspace layout (fp16): Xh[8388608] | Wt[262144]
    _Float16* Xh = (_Float16*)d_ws;
    _Float16* Wt = Xh + XELEMS;

    // pass 0: dtype conversion + W transpose
    prep<<<XELEMS / 4 / 256 + 256, 256, 0, stream>>>((const float4*)X, (f16x4v*)Xh, W, Wt);

    // fused: per (batch, 64-row slice): Y-slice = X_b W into LDS (pipelined),
    // then S = Y X_b^T (pipelined)
    fused<<<256, 512, 0, stream>>>(Xh, Wt, out, bp);

    (void)in_sizes; (void)n_in; (void)out_size; (void)ws_size;
}

// Round 8
// 109.982 us; speedup vs baseline: 1.0970x; 1.0970x over previous
//
#include <hip/hip_runtime.h>
#include <stdint.h>

// Problem constants (fixed by setup_inputs): B=32, N=512, D=512
#define BATCH 32
#define NDIM 512
#define DDIM 512
#define XELEMS (BATCH * NDIM * DDIM)   // 8388608
#define WELEMS (DDIM * DDIM)           // 262144

typedef _Float16 f16x8 __attribute__((ext_vector_type(8)));
typedef _Float16 f16x4v __attribute__((ext_vector_type(4)));
typedef float f32x4 __attribute__((ext_vector_type(4)));

// --- async global -> LDS, 16 bytes per lane (global_load_lds_dwordx4) ---
__device__ __forceinline__ void gl_lds16(const _Float16* g, _Float16* l) {
    __builtin_amdgcn_global_load_lds(
        (const __attribute__((address_space(1))) unsigned int*)(g),
        (__attribute__((address_space(3))) unsigned int*)(l),
        16, 0, 0);
}

// counted vmcnt wait + scheduling fence (rule 18: fence needed so LDS reads/MFMA
// can't be hoisted above the wait by the scheduler)
#define WAITVM(N) do { asm volatile("s_waitcnt vmcnt(" #N ")" ::: "memory"); \
                       __builtin_amdgcn_sched_barrier(0); } while (0)

// ---------------- pass 0: X fp32->fp16 convert  +  W fp32->fp16 transpose ----------
// (unchanged from the 112.8 µs verified kernel)
__global__ __launch_bounds__(256) void prep(const float4* __restrict__ X4,
                                            f16x4v* __restrict__ Xh4,
                                            const float* __restrict__ W,
                                            _Float16* __restrict__ Wt) {
    __shared__ float tile[32][33];
    int bid = blockIdx.x;
    if (bid < XELEMS / 4 / 256) {
        int i = bid * 256 + threadIdx.x;
        float4 v = X4[i];
        f16x4v o;
        o.x = (_Float16)v.x;
        o.y = (_Float16)v.y;
        o.z = (_Float16)v.z;
        o.w = (_Float16)v.w;
        Xh4[i] = o;
    } else {
        int t = bid - XELEMS / 4 / 256;   // 0..255
        int bx = t & 15;                  // e-tile
        int by = t >> 4;                  // d-tile
        int tx = threadIdx.x & 31;
        int ty = threadIdx.x >> 5;        // 0..7
        for (int r = ty; r < 32; r += 8)
            tile[r][tx] = W[(by * 32 + r) * DDIM + bx * 32 + tx];
        __syncthreads();
        for (int r = ty; r < 32; r += 8)
            Wt[(size_t)(bx * 32 + r) * DDIM + by * 32 + tx] = (_Float16)tile[tx][r];
    }
}

// ---------------- fused: S_b = (X_b @ W) @ X_b^T + bias, diag = 0 -------------------
// [R5/R6/R7: BARRIER-FREE counted-vmcnt restructure (R6/R7 = resubmits after infra
//  failures; kernel has never executed). R2/R5 evidence: __syncthreads-based dbuf
//  only got fused 45.5 -> ~41 µs because its implicit `s_waitcnt vmcnt(0)` at every
//  barrier drains the just-issued prefetch (the documented m97-ceiling stall).
//  This problem has structure the generic fix doesn't need: (1) each wave's B-strip
//  (output cols wv*64..+63) is consumed ONLY by the wave that stages it -> self-sync
//  via per-wave counted vmcnt(4), NO barrier; (2) the A-operand (64x512 = 64 KB) is
//  read-only for all of phase 1 (Y->LDS write happens after the K-loop; acc is in
//  registers) -> stage it ONCE behind a single barrier, and let Ylds REUSE the same
//  64 KB after barrier #2. Whole kernel has 3 barriers; vmcnt never drains to 0
//  inside a loop; prefetches stay in flight across the interphase barriers.
//  LDS = AY 64K (A-chunks, then Ylds) + Bs 2x32K dbuf = 128 KB -> 1 block/CU.
//  Swizzle algebra identical to the R2 paper-verified BK=32 scheme (rule-21 pair:
//  staged slot p at row r holds logical k-chunk p ^ ((r>>1)&3); read slot
//  paK = quad ^ ((l16>>1)&3)). MFMA order/K-order unchanged from the R1-verified
//  kernel -> bit-identical accumulation.
//  Audits: vmcnt ledger (R6) — prologue 12 outstanding, WAITVM(4) retires all 8
//  A-loads; steady state 8 -> retire previous tile; peels verified. Fencing (R7) —
//  gl_lds16 can't cross WAITVM ("memory" asm + sched_barrier); gl_lds counts in
//  vmcnt per ISA §7; no hang mode (barriers workgroup-uniform, no spin-waits).]
//
// Grid: 256 blocks = rslice*32 + batch  (blk%8 = batch%8 -> one batch's 8 row-slice
// blocks share an XCD -> X_b (512 KB, read 3x) is L2-resident; Wt resident everywhere).
__global__ __launch_bounds__(512) void fused(const _Float16* __restrict__ Xh,
                                             const _Float16* __restrict__ Wt,
                                             float* __restrict__ Sout,
                                             const float* __restrict__ bias_ptr) {
    // AY: phase 1 = A-chunks, layout [16 ktile][4 rowchunk][16 row][32 col] (fp16);
    //     after barrier2 = Ylds[64][512] (e-chunk XOR-swizzled).
    __shared__ __align__(16) _Float16 AY[64 * 512];        // 64 KB
    __shared__ __align__(16) _Float16 Bs[2][8 * 2048];     // 64 KB: dbuf x (8 waves x 4KB strip)

    const int tid  = threadIdx.x;
    const int lane = tid & 63;
    const int wv   = tid >> 6;        // 0..7
    const int quad = lane >> 4;       // 0..3
    const int l16  = lane & 15;

    // staging decomposition (BK=32): one wave-issue = 16 rows x 32 cols (1 KB).
    const int lr2 = lane >> 2;                    // row within chunk (0..15)
    const int lc2 = lane & 3;                     // physical 16B slot (0..3)
    const int lk2 = (lc2 ^ ((lr2 >> 1) & 3)) * 8; // logical fp16 col to fetch (rule 21)

    // fragment read slot (read side of the same involution; frag rows ≡ l16 mod 16)
    const int paK = (quad ^ ((l16 >> 1) & 3)) * 8;

    const int blk   = blockIdx.x;     // 256 blocks
    const int batch = blk & 31;
    const int r0    = (blk >> 5) * 64;

    const _Float16* Xb = Xh + (size_t)batch * (NDIM * DDIM);

    f32x4 acc[4][4];
#pragma unroll
    for (int i = 0; i < 4; ++i)
#pragma unroll
        for (int j = 0; j < 4; ++j)
            acc[i][j] = (f32x4){0.f, 0.f, 0.f, 0.f};

    // ---- prologue: stage ALL of A (64 rows x 512 cols, 64 chunks; 8 per wave),
    //      then B tile 0 (wave-own strip, 4 chunks). A is oldest -> vmcnt(4) waits A.
#pragma unroll
    for (int c = 0; c < 8; ++c) {
        const int kt = wv * 2 + (c >> 2);         // k-tile 0..15 (2 per wave)
        const int rc = c & 3;                     // row-chunk 0..3
        gl_lds16(Xb + (size_t)(r0 + rc * 16 + lr2) * DDIM + kt * 32 + lk2,
                 &AY[(kt * 4 + rc) * 512]);
    }
#pragma unroll
    for (int t = 0; t < 4; ++t)
        gl_lds16(Wt + (size_t)(wv * 64 + t * 16 + lr2) * DDIM + lk2,
                 &Bs[0][wv * 2048 + t * 512]);
    WAITVM(4);                         // A's 8 loads (oldest) complete; B0 in flight
    __builtin_amdgcn_s_barrier();      // A visible to all waves

    // ================= phase 1: Y = X_b[r0:r0+64][:] @ Wt^T  (16 iters, BK=32) =====
    // Barrier-free: AY read-only, B wave-private. buf = it&1.
#pragma unroll
    for (int it = 0; it < 15; ++it) {
        const int buf = it & 1;
        const int k0 = (it + 1) * 32;
#pragma unroll
        for (int t = 0; t < 4; ++t)    // stage next tile into buf^1 (wave-own)
            gl_lds16(Wt + (size_t)(wv * 64 + t * 16 + lr2) * DDIM + k0 + lk2,
                     &Bs[buf ^ 1][wv * 2048 + t * 512]);
        WAITVM(4);                     // tile it (oldest 4) landed; tile it+1 in flight
        f16x8 a[4], b[4];
#pragma unroll
        for (int mt = 0; mt < 4; ++mt)
            a[mt] = *(const f16x8*)&AY[(it * 4 + mt) * 512 + l16 * 32 + paK];
#pragma unroll
        for (int nt = 0; nt < 4; ++nt)
            b[nt] = *(const f16x8*)&Bs[buf][wv * 2048 + nt * 512 + l16 * 32 + paK];
#pragma unroll
        for (int mt = 0; mt < 4; ++mt)
#pragma unroll
            for (int nt = 0; nt < 4; ++nt)
                acc[mt][nt] = __builtin_amdgcn_mfma_f32_16x16x32_f16(
                    a[mt], b[nt], acc[mt][nt], 0, 0, 0);
    }
    {   // ---- peeled it = 15: prefetch PHASE-2 tile 0 (X_b strip, e0 = 0) instead
        const int buf = 15 & 1;        // = 1; prefetch goes to Bs[0] = phase-2 tile 0
#pragma unroll
        for (int t = 0; t < 4; ++t)
            gl_lds16(Xb + (size_t)(wv * 64 + t * 16 + lr2) * DDIM + lk2,
                     &Bs[buf ^ 1][wv * 2048 + t * 512]);
        WAITVM(4);
        f16x8 a[4], b[4];
#pragma unroll
        for (int mt = 0; mt < 4; ++mt)
            a[mt] = *(const f16x8*)&AY[(15 * 4 + mt) * 512 + l16 * 32 + paK];
#pragma unroll
        for (int nt = 0; nt < 4; ++nt)
            b[nt] = *(const f16x8*)&Bs[buf][wv * 2048 + nt * 512 + l16 * 32 + paK];
#pragma unroll
        for (int mt = 0; mt < 4; ++mt)
#pragma unroll
            for (int nt = 0; nt < 4; ++nt)
                acc[mt][nt] = __builtin_amdgcn_mfma_f32_16x16x32_f16(
                    a[mt], b[nt], acc[mt][nt], 0, 0, 0);
    }

    // ---- interphase. Barrier #2: all waves done READING AY (their MFMAs consumed
    // the a-frags). Then overwrite AY with Ylds (e-chunk XOR-swizzled, R2 formula;
    // C/D layout col = l16, row = quad*4 + r, m89-verified).
    __builtin_amdgcn_s_barrier();
#pragma unroll
    for (int mt = 0; mt < 4; ++mt)
#pragma unroll
        for (int nt = 0; nt < 4; ++nt)
#pragma unroll
            for (int r = 0; r < 4; ++r) {
                int i = mt * 16 + quad * 4 + r;        // Y row (0..63)
                int e = wv * 64 + nt * 16 + l16;       // Y col (0..511)
                int c = e >> 3, j = e & 7;
                AY[i * 512 + (((c ^ (i & 7)) << 3) | j)] = (_Float16)acc[mt][nt][r];
            }
    asm volatile("s_waitcnt lgkmcnt(0)" ::: "memory");  // my ds_writes committed
    __builtin_amdgcn_s_barrier();      // barrier #3: Ylds visible to all waves
    // (phase-2 tile-0 prefetch is STILL in flight across both barriers — raw
    //  s_barrier does not drain vmcnt; that's the whole point.)

    // ================= phase 2: S = Y @ X_b^T  (16 iters, BK=32, barrier-free) =====
#pragma unroll
    for (int i = 0; i < 4; ++i)
#pragma unroll
        for (int j = 0; j < 4; ++j)
            acc[i][j] = (f32x4){0.f, 0.f, 0.f, 0.f};

#pragma unroll
    for (int it = 0; it < 15; ++it) {
        const int buf = it & 1;
        const int e0 = (it + 1) * 32;
#pragma unroll
        for (int t = 0; t < 4; ++t)    // stage next e-tile (wave-own X_b strip)
            gl_lds16(Xb + (size_t)(wv * 64 + t * 16 + lr2) * DDIM + e0 + lk2,
                     &Bs[buf ^ 1][wv * 2048 + t * 512]);
        WAITVM(4);
        const int pay = (((it * 4 + quad) ^ (l16 & 7)) * 8);  // Ylds swizzled col
        f16x8 a[4], b[4];
#pragma unroll
        for (int mt = 0; mt < 4; ++mt)
            a[mt] = *(const f16x8*)&AY[(mt * 16 + l16) * 512 + pay];
#pragma unroll
        for (int nt = 0; nt < 4; ++nt)
            b[nt] = *(const f16x8*)&Bs[buf][wv * 2048 + nt * 512 + l16 * 32 + paK];
#pragma unroll
        for (int mt = 0; mt < 4; ++mt)
#pragma unroll
            for (int nt = 0; nt < 4; ++nt)
                acc[mt][nt] = __builtin_amdgcn_mfma_f32_16x16x32_f16(
                    a[mt], b[nt], acc[mt][nt], 0, 0, 0);
    }
    {   // ---- peeled it = 15: nothing left to stage; drain the last own-tile
        const int buf = 15 & 1;
        WAITVM(0);
        const int pay = (((15 * 4 + quad) ^ (l16 & 7)) * 8);
        f16x8 a[4], b[4];
#pragma unroll
        for (int mt = 0; mt < 4; ++mt)
            a[mt] = *(const f16x8*)&AY[(mt * 16 + l16) * 512 + pay];
#pragma unroll
        for (int nt = 0; nt < 4; ++nt)
            b[nt] = *(const f16x8*)&Bs[buf][wv * 2048 + nt * 512 + l16 * 32 + paK];
#pragma unroll
        for (int mt = 0; mt < 4; ++mt)
#pragma unroll
            for (int nt = 0; nt < 4; ++nt)
                acc[mt][nt] = __builtin_amdgcn_mfma_f32_16x16x32_f16(
                    a[mt], b[nt], acc[mt][nt], 0, 0, 0);
    }

    // ---- epilogue: bias, zero diagonal, fp32 store (register-only; no barrier)
    const float bias = bias_ptr[0];
#pragma unroll
    for (int mt = 0; mt < 4; ++mt)
#pragma unroll
        for (int nt = 0; nt < 4; ++nt)
#pragma unroll
            for (int r = 0; r < 4; ++r) {
                int gi = r0 + mt * 16 + quad * 4 + r;   // row within batch (0..511)
                int gj = wv * 64 + nt * 16 + l16;       // col within batch (0..511)
                float v = acc[mt][nt][r] + bias;
                if (gi == gj) v = 0.f;
                Sout[((size_t)batch * NDIM + gi) * NDIM + gj] = v;
            }
}

extern "C" void kernel_launch(void* const* d_in, const int* in_sizes, int n_in,
                              void* d_out, int out_size, void* d_ws, size_t ws_size,
                              hipStream_t stream) {
    const float* X  = (const float*)d_in[0];   // (32, 512, 512) fp32
    const float* W  = (const float*)d_in[1];   // (512, 512) fp32
    const float* bp = (const float*)d_in[2];   // scalar fp32
    float* out = (float*)d_out;                // (32, 512, 512) fp32

    // workspace layout (fp16): Xh[8388608] | Wt[262144]
    _Float16* Xh = (_Float16*)d_ws;
    _Float16* Wt = Xh + XELEMS;

    // pass 0: dtype conversion + W transpose
    prep<<<XELEMS / 4 / 256 + 256, 256, 0, stream>>>((const float4*)X, (f16x4v*)Xh, W, Wt);

    // fused: per (batch, 64-row slice): Y-slice = X_b W (A staged once, barrier-free
    // counted-vmcnt K-loop) -> Ylds (reuses A's LDS) -> S = Y X_b^T (barrier-free)
    fused<<<256, 512, 0, stream>>>(Xh, Wt, out, bp);

    (void)in_sizes; (void)n_in; (void)out_size; (void)ws_size;
}